// Round 5
// baseline (604.906 us; speedup 1.0000x reference)
//
#include <hip/hip_runtime.h>
#include <stdint.h>

#define N_ROWS 8192
#define D 384
#define K_CODES 25000
#define CAND_CAP 96
#define SPLIT 12500
#define NTC 98          // ceil(12500/128)

typedef __attribute__((ext_vector_type(8))) short bf16x8;
typedef __attribute__((ext_vector_type(4))) float f32x4;

// ---- ws layout (bytes) ----
#define WS_XB    0ULL                          // 8192*384*2   = 6291456
#define WS_CBB   6291456ULL                    // 25000*384*2  = 19200000
#define WS_CAND  25491456ULL                   // 8192*96*4    = 3145728
#define WS_FKEY  28637184ULL                   // 8192*8
#define WS_S     28702720ULL                   // 8192*4
#define WS_MG    28735488ULL                   // 8192*4
#define WS_CNT   28768256ULL                   // 8192*4
#define WS_NEED  28801024ULL

__device__ __forceinline__ unsigned int mono_bits(float f) {
    unsigned int u = __float_as_uint(f);
    return u ^ ((u & 0x80000000u) ? 0xFFFFFFFFu : 0x80000000u);
}
__device__ __forceinline__ unsigned short f2bf_rne(float f) {
    unsigned int u = __float_as_uint(f);
    return (unsigned short)((u + 0x7FFFu + ((u >> 16) & 1u)) >> 16);
}

// ---------------- fp32 -> bf16 conversion ---------------------------------------------
__global__ __launch_bounds__(256) void cvt_bf16_kernel(const float4* __restrict__ src,
                                                       ushort4* __restrict__ dst, int n4)
{
    int i = blockIdx.x * 256 + threadIdx.x;
    if (i >= n4) return;
    float4 v = src[i];
    ushort4 o;
    o.x = f2bf_rne(v.x); o.y = f2bf_rne(v.y); o.z = f2bf_rne(v.z); o.w = f2bf_rne(v.w);
    dst[i] = o;
}

// ---------------- prep: S (numpy pairwise order), margin, cnt init --------------------
__global__ __launch_bounds__(256) void prep_kernel(const float* __restrict__ feat,
                                                   float* __restrict__ S,
                                                   float* __restrict__ Mg,
                                                   unsigned int* __restrict__ cnt)
{
#pragma clang fp contract(off)
    int row = blockIdx.x * 256 + threadIdx.x;
    if (row >= N_ROWS) return;
    if (cnt) cnt[row] = 0u;
    const float* x = feat + (size_t)row * D;
    float Bres[4];
#pragma unroll
    for (int b = 0; b < 4; ++b) {
        const float* q = x + b * 96;
        float v[8][4];
#pragma unroll
        for (int j = 0; j < 8; ++j)
#pragma unroll
            for (int l = 0; l < 4; ++l) {
                float t = q[4 * j + l];
                v[j][l] = t * t;
            }
#pragma unroll
        for (int i = 32; i <= 64; i += 32)
#pragma unroll
            for (int j = 0; j < 8; ++j)
#pragma unroll
                for (int l = 0; l < 4; ++l) {
                    float t = q[i + 4 * j + l];
                    float p = t * t;
                    v[j][l] = v[j][l] + p;
                }
        float c[4];
#pragma unroll
        for (int l = 0; l < 4; ++l)
            c[l] = ((v[0][l] + v[1][l]) + (v[2][l] + v[3][l]))
                 + ((v[4][l] + v[5][l]) + (v[6][l] + v[7][l]));
        Bres[b] = (c[0] + c[1]) + (c[2] + c[3]);
    }
    float s = (Bres[0] + Bres[1]) + (Bres[2] + Bres[3]);
    S[row] = s;
    if (Mg) Mg[row] = scalbnf(1.0f, ilogbf(s) - 23) + 1.2e-4f;  // ulp(s) + slack
}

// ---------------- MFMA scan: features-in-registers, codes streamed through LDS --------
// 256 blocks = 128 row-tiles (64 rows) x 2 code-splits (12500 codes). sp = bid&1 so
// each XCD (bid%8) streams one split -> L2-coherent code stream across its 32 CUs.
// 4 waves/block: wave owns 32 distinct codes/tile and ALL 64 rows (B-frags in 192 VGPR,
// loaded once). Per kt-step/wave: 2 ds_read_b128 per ks (af only) feeding 8 MFMAs ->
// M/R = 4 (2x the R4 ratio). Double-buffered Ct (32KB LDS), stage(next) before compute.
#define STAGE(BUF, NT, KT)                                                                \
    do {                                                                                  \
        const int nn0_ = kbase + (NT) * 128;                                              \
        _Pragma("unroll")                                                                 \
        for (int q = 0; q < 4; ++q) {                                                     \
            int code_ = nn0_ + rq[q];                                                     \
            code_ = code_ > K_CODES - 1 ? K_CODES - 1 : code_;                            \
            const ushort* ca_ = cbb + (size_t)code_ * D + (KT) * 64 + lcq[q] * 8;         \
            __builtin_amdgcn_global_load_lds(                                             \
                (const __attribute__((address_space(1))) void*)ca_,                       \
                (__attribute__((address_space(3))) void*)&Ct[BUF][sq[q] * 8], 16, 0, 0);  \
        }                                                                                 \
    } while (0)

__global__ __launch_bounds__(256) void mfma_scan(const ushort* __restrict__ xb,
                                                 const ushort* __restrict__ cbb,
                                                 const float* __restrict__ Mg,
                                                 unsigned int* __restrict__ cnt,
                                                 unsigned int* __restrict__ cand)
{
    __shared__ ushort Ct[2][128 * 64];

    const int tid = threadIdx.x;
    const int sp = blockIdx.x & 1;
    const int rt = blockIdx.x >> 1;
    const int r0 = rt * 64;
    const int kbase = sp * SPLIT;

    const int wave = tid >> 6, lane = tid & 63, ln15 = lane & 15, l16 = lane >> 4;
    const int cw = wave * 32;

    int sq[4], rq[4], lcq[4];
#pragma unroll
    for (int q = 0; q < 4; ++q) {
        int s = q * 256 + tid;
        sq[q] = s; rq[q] = s >> 3; lcq[q] = (s & 7) ^ ((s >> 3) & 7);
    }

    // B-operand (features): 64 rows x 384 k resident in registers (4 ni x 12 k-slices)
    bf16x8 bfr[4][12];
#pragma unroll
    for (int ni = 0; ni < 4; ++ni)
#pragma unroll
        for (int s = 0; s < 12; ++s)
            bfr[ni][s] = *(const bf16x8*)(xb + (size_t)(r0 + ni * 16 + ln15) * D
                                          + s * 32 + l16 * 8);

    float run[4], mg[4];
#pragma unroll
    for (int ni = 0; ni < 4; ++ni) {
        mg[ni] = Mg[r0 + ni * 16 + ln15];
        run[ni] = __int_as_float(0x7F800000);
    }

    STAGE(0, 0, 0);
    int cur = 0;

#pragma unroll 1
    for (int nt = 0; nt < NTC; ++nt) {
        const int n0 = kbase + nt * 128;
        f32x4 acc[2][4] = {};
#pragma unroll
        for (int kt = 0; kt < 6; ++kt) {
            __syncthreads();              // drains DMA into cur (issued a full kt ago)
            if (kt < 5) STAGE(cur ^ 1, nt, kt + 1);
            else if (nt + 1 < NTC) STAGE(cur ^ 1, nt + 1, 0);
#pragma unroll
            for (int ks = 0; ks < 2; ++ks) {
                bf16x8 af[2];
#pragma unroll
                for (int mi = 0; mi < 2; ++mi) {
                    int c = cw + mi * 16 + ln15;
                    int lc = ks * 4 + l16;
                    af[mi] = *(const bf16x8*)&Ct[cur][c * 64 + ((lc ^ (c & 7)) << 3)];
                }
#pragma unroll
                for (int mi = 0; mi < 2; ++mi)
#pragma unroll
                    for (int ni = 0; ni < 4; ++ni)
                        acc[mi][ni] = __builtin_amdgcn_mfma_f32_16x16x32_bf16(
                            af[mi], bfr[ni][kt * 2 + ks], acc[mi][ni], 0, 0, 0);
            }
            cur ^= 1;
        }
        // epilogue: per-row running min of v = -2*dot; append within margin
#pragma unroll
        for (int ni = 0; ni < 4; ++ni) {
            float mx = acc[0][ni][0];
#pragma unroll
            for (int mi = 0; mi < 2; ++mi)
#pragma unroll
                for (int rr = 0; rr < 4; ++rr) mx = fmaxf(mx, acc[mi][ni][rr]);
            mx = fmaxf(mx, __shfl_xor(mx, 16));
            mx = fmaxf(mx, __shfl_xor(mx, 32));
            float vt = -2.0f * mx;
            float rn = fminf(run[ni], vt);
            run[ni] = rn;
            if (vt <= rn + mg[ni]) {      // rare: record or near-record in this tile
                float T = rn + mg[ni];
                int row = r0 + ni * 16 + ln15;
#pragma unroll
                for (int mi = 0; mi < 2; ++mi)
#pragma unroll
                    for (int rr = 0; rr < 4; ++rr) {
                        float v = -2.0f * acc[mi][ni][rr];
                        int c = n0 + cw + mi * 16 + l16 * 4 + rr;
                        if (v <= T && c < K_CODES) {
                            unsigned int idx = atomicAdd(&cnt[row], 1u);
                            if (idx < (unsigned)CAND_CAP)
                                cand[(size_t)row * CAND_CAP + idx] = (unsigned int)c;
                        }
                    }
            }
        }
    }
}

// ---------------- exact fp32 rescore of candidates (verified chain order) -------------
__global__ __launch_bounds__(256) void rescore_kernel(const float* __restrict__ feat,
                                                      const float* __restrict__ cb,
                                                      const float* __restrict__ S,
                                                      const unsigned int* __restrict__ cnt,
                                                      const unsigned int* __restrict__ cand,
                                                      unsigned long long* __restrict__ fkey)
{
    int row = blockIdx.x * 4 + (threadIdx.x >> 6);
    int lane = threadIdx.x & 63;
    unsigned int c = cnt[row];
    if (c > (unsigned)CAND_CAP) return;       // rescue kernel owns this row
    const float* x = feat + (size_t)row * D;
    float s = S[row];
    unsigned long long best = ~0ULL;
#pragma unroll
    for (int base = 0; base < CAND_CAP; base += 64) {
        int ci = base + lane;
        if (ci < (int)c) {
            unsigned int n = cand[(size_t)row * CAND_CAP + ci];
            const float* cr = cb + (size_t)n * D;
            float m = 0.f;
            for (int d = 0; d < D; ++d) m = fmaf(x[d], cr[d], m);
            float dd = s - 2.0f * m;
            unsigned long long key = ((unsigned long long)mono_bits(dd) << 32) | n;
            best = key < best ? key : best;
        }
    }
#pragma unroll
    for (int off = 1; off < 64; off <<= 1) {
        unsigned long long o = __shfl_xor(best, off);
        best = o < best ? o : best;
    }
    if (lane == 0) fkey[row] = best;
}

// ---------------- rescue: full exact scan for overflowed rows (expected: none) --------
__global__ __launch_bounds__(256) void rescue_kernel(const float* __restrict__ feat,
                                                     const float* __restrict__ cb,
                                                     const float* __restrict__ S,
                                                     const unsigned int* __restrict__ cnt,
                                                     unsigned long long* __restrict__ fkey)
{
    __shared__ unsigned long long red[256];
    for (int row = blockIdx.x; row < N_ROWS; row += gridDim.x) {
        if (cnt[row] <= (unsigned)CAND_CAP) continue;
        const float* x = feat + (size_t)row * D;
        float s = S[row];
        unsigned long long best = ~0ULL;
        for (int nb = threadIdx.x * 4; nb < K_CODES; nb += 1024) {
            float m[4] = {0.f, 0.f, 0.f, 0.f};
            for (int d = 0; d < D; ++d) {
                float xv = x[d];
#pragma unroll
                for (int j = 0; j < 4; ++j)
                    if (nb + j < K_CODES) m[j] = fmaf(xv, cb[(size_t)(nb + j) * D + d], m[j]);
            }
#pragma unroll
            for (int j = 0; j < 4; ++j)
                if (nb + j < K_CODES) {
                    float dd = s - 2.0f * m[j];
                    unsigned long long key =
                        ((unsigned long long)mono_bits(dd) << 32) | (unsigned)(nb + j);
                    best = key < best ? key : best;
                }
        }
        red[threadIdx.x] = best;
        __syncthreads();
        for (int st = 128; st > 0; st >>= 1) {
            if (threadIdx.x < st)
                if (red[threadIdx.x + st] < red[threadIdx.x]) red[threadIdx.x] = red[threadIdx.x + st];
            __syncthreads();
        }
        if (threadIdx.x == 0) fkey[row] = red[0];
        __syncthreads();
    }
}

// ---------------- fallback (round-2 proven fp32 path) ---------------------------------
__global__ __launch_bounds__(256) void gemm_argmin_fb(const float* __restrict__ feat,
                                                      const float* __restrict__ cb,
                                                      const float* __restrict__ S,
                                                      unsigned long long* __restrict__ keys)
{
    __shared__ float4 A4[64][16];
    __shared__ float4 B4[64][16];
    const int tid = threadIdx.x;
    const int tr = tid & 15;
    const int tk = tid >> 4;
    const int rt = blockIdx.x & 127;
    const int ks = blockIdx.x >> 7;
    const int r0 = rt * 64;
    const int kbase = ks * 6250;
    float s_reg[4];
#pragma unroll
    for (int i = 0; i < 4; ++i) s_reg[i] = S[r0 + 4 * tr + i];
    unsigned long long best[4];
#pragma unroll
    for (int i = 0; i < 4; ++i) best[i] = ~0ULL;
    for (int kt = 0; kt < 98; ++kt) {
        const int k0 = kbase + kt * 64;
        float acc[4][4];
#pragma unroll
        for (int ii = 0; ii < 4; ++ii)
#pragma unroll
            for (int jj = 0; jj < 4; ++jj) acc[ii][jj] = 0.f;
        for (int dc = 0; dc < 6; ++dc) {
            __syncthreads();
#pragma unroll
            for (int t = 0; t < 4; ++t) {
                int fidx = t * 256 + tid;
                int r = fidx >> 4;
                int c4 = fidx & 15;
                const float4* asrc = reinterpret_cast<const float4*>(feat + (size_t)(r0 + r) * D + dc * 64);
                A4[r][c4 ^ ((r >> 2) & 7)] = asrc[c4];
                int k = k0 + r;
                float4 bval = make_float4(0.f, 0.f, 0.f, 0.f);
                if (k < K_CODES) {
                    const float4* bsrc = reinterpret_cast<const float4*>(cb + (size_t)k * D + dc * 64);
                    bval = bsrc[c4];
                }
                B4[r][c4 ^ ((r >> 2) & 7)] = bval;
            }
            __syncthreads();
#pragma unroll 4
            for (int dk4 = 0; dk4 < 16; ++dk4) {
                float4 av[4], bv[4];
#pragma unroll
                for (int i = 0; i < 4; ++i) av[i] = A4[4 * tr + i][dk4 ^ (tr & 7)];
#pragma unroll
                for (int i = 0; i < 4; ++i) bv[i] = B4[4 * tk + i][dk4 ^ (tk & 7)];
#pragma unroll
                for (int ri = 0; ri < 4; ++ri)
#pragma unroll
                    for (int ki = 0; ki < 4; ++ki) {
                        acc[ri][ki] = fmaf(av[ri].x, bv[ki].x, acc[ri][ki]);
                        acc[ri][ki] = fmaf(av[ri].y, bv[ki].y, acc[ri][ki]);
                        acc[ri][ki] = fmaf(av[ri].z, bv[ki].z, acc[ri][ki]);
                        acc[ri][ki] = fmaf(av[ri].w, bv[ki].w, acc[ri][ki]);
                    }
            }
        }
#pragma unroll
        for (int ri = 0; ri < 4; ++ri)
#pragma unroll
            for (int ki = 0; ki < 4; ++ki) {
                int k = k0 + 4 * tk + ki;
                if (k < K_CODES) {
                    float d = s_reg[ri] - 2.0f * acc[ri][ki];
                    unsigned long long key =
                        ((unsigned long long)mono_bits(d) << 32) | (unsigned long long)(unsigned)k;
                    best[ri] = key < best[ri] ? key : best[ri];
                }
            }
    }
#pragma unroll
    for (int ri = 0; ri < 4; ++ri)
        atomicMin(&keys[r0 + 4 * tr + ri], best[ri]);
}

__global__ __launch_bounds__(256) void initkeys_kernel(unsigned long long* __restrict__ keys)
{
    int r = blockIdx.x * 256 + threadIdx.x;
    if (r < N_ROWS) keys[r] = ~0ULL;
}

// ---------------- output kernels -------------------------------------------------------
__global__ __launch_bounds__(256) void finalize_kernel(const unsigned long long* __restrict__ keys,
                                                       float* __restrict__ out)
{
    int r = blockIdx.x * 256 + threadIdx.x;
    if (r < N_ROWS) out[r] = (float)(unsigned int)(keys[r] & 0xFFFFFFFFULL);
}
__global__ __launch_bounds__(256) void copyfeat_kernel(const float4* __restrict__ src,
                                                       float4* __restrict__ dst, int n4)
{
    int i = blockIdx.x * 256 + threadIdx.x;
    if (i < n4) dst[i] = src[i];
}

extern "C" void kernel_launch(void* const* d_in, const int* in_sizes, int n_in,
                              void* d_out, int out_size, void* d_ws, size_t ws_size,
                              hipStream_t stream)
{
    const float* feat = (const float*)d_in[0];   // [8192, 384]
    const float* cb   = (const float*)d_in[1];   // [25000, 384]
    float* out = (float*)d_out;

    char* ws = (char*)d_ws;

    if (ws_size >= WS_NEED) {
        ushort* xb  = (ushort*)(ws + WS_XB);
        ushort* cbb = (ushort*)(ws + WS_CBB);
        unsigned int* cand = (unsigned int*)(ws + WS_CAND);
        unsigned long long* fkey = (unsigned long long*)(ws + WS_FKEY);
        float* S   = (float*)(ws + WS_S);
        float* Mg  = (float*)(ws + WS_MG);
        unsigned int* cnt = (unsigned int*)(ws + WS_CNT);

        cvt_bf16_kernel<<<3072, 256, 0, stream>>>((const float4*)feat, (ushort4*)xb,
                                                  N_ROWS * D / 4);
        cvt_bf16_kernel<<<9375, 256, 0, stream>>>((const float4*)cb, (ushort4*)cbb,
                                                  K_CODES * D / 4);
        prep_kernel<<<N_ROWS / 256, 256, 0, stream>>>(feat, S, Mg, cnt);
        mfma_scan<<<256, 256, 0, stream>>>(xb, cbb, Mg, cnt, cand);
        rescore_kernel<<<N_ROWS / 4, 256, 0, stream>>>(feat, cb, S, cnt, cand, fkey);
        rescue_kernel<<<256, 256, 0, stream>>>(feat, cb, S, cnt, fkey);
        finalize_kernel<<<N_ROWS / 256, 256, 0, stream>>>(fkey, out);
    } else {
        unsigned long long* keys = (unsigned long long*)ws;
        float* S = (float*)(ws + 65536);
        initkeys_kernel<<<N_ROWS / 256, 256, 0, stream>>>(keys);
        prep_kernel<<<N_ROWS / 256, 256, 0, stream>>>(feat, S, nullptr, nullptr);
        gemm_argmin_fb<<<128 * 4, 256, 0, stream>>>(feat, cb, S, keys);
        finalize_kernel<<<N_ROWS / 256, 256, 0, stream>>>(keys, out);
    }
    copyfeat_kernel<<<(N_ROWS * D / 4) / 256, 256, 0, stream>>>(
        (const float4*)feat, (float4*)(out + N_ROWS), N_ROWS * D / 4);
}